// Round 1
// baseline (599.056 us; speedup 1.0000x reference)
//
#include <hip/hip_runtime.h>

// Problem constants (B, Lq, Lkv, D) fixed by the reference setup.
#define BATCH 16
#define LQ    1024
#define LK    1024
#define DD    512

// Tiling: 64x64 tile, BK=16, 256 threads, 4x4 microtile per thread.
constexpr int BM = 64, BN = 64, BK = 16, PAD = 4;

// ---------------------------------------------------------------------------
// GEMM 1: S[b] = Q[b] @ V[b]^T   (NT gemm: both operands row-major, K=D contiguous)
// grid (LQ/BM, LK/BN, BATCH), block 256
// ---------------------------------------------------------------------------
__global__ __launch_bounds__(256) void gemm_qvt(const float* __restrict__ Q,
                                                const float* __restrict__ V,
                                                float* __restrict__ S) {
    __shared__ __align__(16) float sA[BK][BM + PAD];
    __shared__ __align__(16) float sB[BK][BN + PAD];

    const int b = blockIdx.z;
    const float* Qb = Q + (size_t)b * LQ * DD + (size_t)blockIdx.x * BM * DD;
    const float* Vb = V + (size_t)b * LK * DD + (size_t)blockIdx.y * BN * DD;
    float*       Sb = S + (size_t)b * LQ * LK;

    const int tid = threadIdx.x;
    const int tx  = tid & 15;        // 0..15 -> output cols
    const int ty  = tid >> 4;        // 0..15 -> output rows
    // staging loader: each thread loads one float4 of Q and V
    const int lr  = tid >> 2;        // 0..63 (tile row)
    const int lc  = (tid & 3) << 2;  // 0,4,8,12 (k offset)

    float acc[4][4] = {};

    for (int k0 = 0; k0 < DD; k0 += BK) {
        float4 qa = *(const float4*)(Qb + (size_t)lr * DD + k0 + lc);
        float4 va = *(const float4*)(Vb + (size_t)lr * DD + k0 + lc);
        __syncthreads();
        sA[lc + 0][lr] = qa.x; sA[lc + 1][lr] = qa.y;
        sA[lc + 2][lr] = qa.z; sA[lc + 3][lr] = qa.w;
        sB[lc + 0][lr] = va.x; sB[lc + 1][lr] = va.y;
        sB[lc + 2][lr] = va.z; sB[lc + 3][lr] = va.w;
        __syncthreads();
#pragma unroll
        for (int k = 0; k < BK; ++k) {
            float4 a4 = *(const float4*)&sA[k][ty << 2];
            float4 b4 = *(const float4*)&sB[k][tx << 2];
            float a[4] = {a4.x, a4.y, a4.z, a4.w};
            float bb[4] = {b4.x, b4.y, b4.z, b4.w};
#pragma unroll
            for (int i = 0; i < 4; ++i)
#pragma unroll
                for (int j = 0; j < 4; ++j)
                    acc[i][j] = fmaf(a[i], bb[j], acc[i][j]);
        }
    }

    const int r0 = blockIdx.x * BM + (ty << 2);
    const int c0 = blockIdx.y * BN + (tx << 2);
#pragma unroll
    for (int i = 0; i < 4; ++i) {
        float4 o = {acc[i][0], acc[i][1], acc[i][2], acc[i][3]};
        *(float4*)(Sb + (size_t)(r0 + i) * LK + c0) = o;
    }
}

// ---------------------------------------------------------------------------
// Row softmax in place: 16384 rows of 1024. One block (256 thr) per row.
// Scores reach ~±85 (no 1/sqrt(d) scale) -> must subtract row max.
// ---------------------------------------------------------------------------
__global__ __launch_bounds__(256) void softmax_rows(float* __restrict__ S) {
    float* p = S + (size_t)blockIdx.x * LK;
    const int t = threadIdx.x;

    float4 v = *(float4*)(p + (t << 2));
    float m = fmaxf(fmaxf(v.x, v.y), fmaxf(v.z, v.w));
#pragma unroll
    for (int off = 1; off < 64; off <<= 1)
        m = fmaxf(m, __shfl_xor(m, off, 64));

    __shared__ float redm[4];
    __shared__ float reds[4];
    const int wave = t >> 6, lane = t & 63;
    if (lane == 0) redm[wave] = m;
    __syncthreads();
    m = fmaxf(fmaxf(redm[0], redm[1]), fmaxf(redm[2], redm[3]));

    v.x = __expf(v.x - m); v.y = __expf(v.y - m);
    v.z = __expf(v.z - m); v.w = __expf(v.w - m);
    float s = (v.x + v.y) + (v.z + v.w);
#pragma unroll
    for (int off = 1; off < 64; off <<= 1)
        s += __shfl_xor(s, off, 64);
    if (lane == 0) reds[wave] = s;
    __syncthreads();
    s = (reds[0] + reds[1]) + (reds[2] + reds[3]);

    const float inv = 1.0f / s;
    v.x *= inv; v.y *= inv; v.z *= inv; v.w *= inv;
    *(float4*)(p + (t << 2)) = v;
}

// ---------------------------------------------------------------------------
// GEMM 2: C[b] = P[b] @ V[b]   (NN gemm: P [LQ,LK], V [LK,DD])
// grid (LQ/BM, DD/BN, BATCH), block 256
// ---------------------------------------------------------------------------
__global__ __launch_bounds__(256) void gemm_pv(const float* __restrict__ P,
                                               const float* __restrict__ V,
                                               float* __restrict__ C) {
    __shared__ __align__(16) float sA[BK][BM + PAD];
    __shared__ __align__(16) float sB[BK][BN + PAD];

    const int b = blockIdx.z;
    const float* Pb = P + (size_t)b * LQ * LK + (size_t)blockIdx.x * BM * LK;
    const float* Vb = V + (size_t)b * LK * DD;
    float*       Cb = C + (size_t)b * LQ * DD;

    const int tid = threadIdx.x;
    const int tx  = tid & 15;
    const int ty  = tid >> 4;
    const int lr  = tid >> 2;        // A-tile row 0..63
    const int lc  = (tid & 3) << 2;  // A-tile k offset
    const int bkr = tid >> 4;        // B-tile k row 0..15
    const int bcg = (tid & 15) << 2; // B-tile col offset 0..60
    const int n0  = blockIdx.y * BN;

    float acc[4][4] = {};

    for (int k0 = 0; k0 < LK; k0 += BK) {
        float4 pa = *(const float4*)(Pb + (size_t)lr * LK + k0 + lc);
        float4 vb = *(const float4*)(Vb + (size_t)(k0 + bkr) * DD + n0 + bcg);
        __syncthreads();
        sA[lc + 0][lr] = pa.x; sA[lc + 1][lr] = pa.y;
        sA[lc + 2][lr] = pa.z; sA[lc + 3][lr] = pa.w;
        *(float4*)&sB[bkr][bcg] = vb;
        __syncthreads();
#pragma unroll
        for (int k = 0; k < BK; ++k) {
            float4 a4 = *(const float4*)&sA[k][ty << 2];
            float4 b4 = *(const float4*)&sB[k][tx << 2];
            float a[4] = {a4.x, a4.y, a4.z, a4.w};
            float bb[4] = {b4.x, b4.y, b4.z, b4.w};
#pragma unroll
            for (int i = 0; i < 4; ++i)
#pragma unroll
                for (int j = 0; j < 4; ++j)
                    acc[i][j] = fmaf(a[i], bb[j], acc[i][j]);
        }
    }

    const int r0 = blockIdx.x * BM + (ty << 2);
    const int c0 = n0 + (tx << 2);
#pragma unroll
    for (int i = 0; i < 4; ++i) {
        float4 o = {acc[i][0], acc[i][1], acc[i][2], acc[i][3]};
        *(float4*)(Cb + (size_t)(r0 + i) * DD + c0) = o;
    }
}

// ---------------------------------------------------------------------------
extern "C" void kernel_launch(void* const* d_in, const int* in_sizes, int n_in,
                              void* d_out, int out_size, void* d_ws, size_t ws_size,
                              hipStream_t stream) {
    const float* Q = (const float*)d_in[0];
    const float* V = (const float*)d_in[1];

    float* ctx  = (float*)d_out;                       // [16,1024,512]
    float* attn = ctx + (size_t)BATCH * LQ * DD;       // [16,1024,1024]

    // S = Q @ V^T written straight into the attn output region (no d_ws needed)
    gemm_qvt<<<dim3(LQ / BM, LK / BN, BATCH), 256, 0, stream>>>(Q, V, attn);
    // softmax in place
    softmax_rows<<<dim3(BATCH * LQ), 256, 0, stream>>>(attn);
    // context = P @ V
    gemm_pv<<<dim3(LQ / BM, DD / BN, BATCH), 256, 0, stream>>>(attn, V, ctx);
}

// Round 2
// 331.679 us; speedup vs baseline: 1.8061x; 1.8061x over previous
//
#include <hip/hip_runtime.h>

#define BATCH 16
#define LQ    1024
#define LK    1024
#define DD    512

typedef unsigned int u32;
typedef unsigned short ushort_t;
typedef short short8 __attribute__((ext_vector_type(8)));
typedef float f32x4 __attribute__((ext_vector_type(4)));
#define AS1 __attribute__((address_space(1)))
#define AS3 __attribute__((address_space(3)))

// ---------------------------------------------------------------------------
// split fp32 -> (bf16 hi by truncation, bf16 lo = trunc(x - hi)) packed pairs
// ---------------------------------------------------------------------------
__device__ __forceinline__ void split2(float x0, float x1, u32& hp, u32& lp) {
    u32 u0 = __float_as_uint(x0), u1 = __float_as_uint(x1);
    hp = __builtin_amdgcn_perm(u1, u0, 0x07060302u);   // (hi0, hi1) as 2 ushorts
    float l0 = x0 - __uint_as_float(u0 & 0xffff0000u);
    float l1 = x1 - __uint_as_float(u1 & 0xffff0000u);
    lp = __builtin_amdgcn_perm(__float_as_uint(l1), __float_as_uint(l0), 0x07060302u);
}

// ---------------------------------------------------------------------------
// Convert Q (linear): 8 elements / thread
// ---------------------------------------------------------------------------
__global__ __launch_bounds__(256) void convert_q(const float* __restrict__ x,
                                                 ushort_t* __restrict__ hi,
                                                 ushort_t* __restrict__ lo) {
    size_t i = ((size_t)blockIdx.x * 256 + threadIdx.x) * 8;
    float4 a = *(const float4*)(x + i);
    float4 b = *(const float4*)(x + i + 4);
    u32 h0, h1, h2, h3, l0, l1, l2, l3;
    split2(a.x, a.y, h0, l0); split2(a.z, a.w, h1, l1);
    split2(b.x, b.y, h2, l2); split2(b.z, b.w, h3, l3);
    uint4 hv; hv.x = h0; hv.y = h1; hv.z = h2; hv.w = h3;
    uint4 lv; lv.x = l0; lv.y = l1; lv.z = l2; lv.w = l3;
    *(uint4*)(hi + i) = hv;
    *(uint4*)(lo + i) = lv;
}

// ---------------------------------------------------------------------------
// Convert V: straight hi/lo [1024 x 512] AND transposed hi/lo [512 x 1024]
// 32x32 tiles via LDS. grid (512/32, 1024/32, BATCH)
// ---------------------------------------------------------------------------
__global__ __launch_bounds__(256) void convert_v(const float* __restrict__ V,
                                                 ushort_t* __restrict__ vhi, ushort_t* __restrict__ vlo,
                                                 ushort_t* __restrict__ vthi, ushort_t* __restrict__ vtlo) {
    __shared__ float tile[32][33];
    const int b = blockIdx.z;
    const int c0 = blockIdx.x * 32;   // d (col) offset
    const int r0 = blockIdx.y * 32;   // kv (row) offset
    const float* Vb = V + (size_t)b * LK * DD;
    const int t = threadIdx.x;
    const int r = t >> 3, c4 = (t & 7) * 4;

    float4 f = *(const float4*)(Vb + (size_t)(r0 + r) * DD + c0 + c4);
    tile[r][c4 + 0] = f.x; tile[r][c4 + 1] = f.y;
    tile[r][c4 + 2] = f.z; tile[r][c4 + 3] = f.w;

    // straight output (no LDS needed)
    {
        u32 h0, h1, l0, l1;
        split2(f.x, f.y, h0, l0); split2(f.z, f.w, h1, l1);
        size_t o = (size_t)b * LK * DD + (size_t)(r0 + r) * DD + c0 + c4;
        uint2 hv; hv.x = h0; hv.y = h1;
        uint2 lv; lv.x = l0; lv.y = l1;
        *(uint2*)(vhi + o) = hv;
        *(uint2*)(vlo + o) = lv;
    }
    __syncthreads();
    // transposed output: Vt[n][k], n = d index, k = kv index
    {
        const int n = t >> 3, k4 = (t & 7) * 4;
        float x0 = tile[k4 + 0][n], x1 = tile[k4 + 1][n];
        float x2 = tile[k4 + 2][n], x3 = tile[k4 + 3][n];
        u32 h0, h1, l0, l1;
        split2(x0, x1, h0, l0); split2(x2, x3, h1, l1);
        size_t o = (size_t)b * DD * LK + (size_t)(c0 + n) * LK + r0 + k4;
        uint2 hv; hv.x = h0; hv.y = h1;
        uint2 lv; lv.x = l0; lv.y = l1;
        *(uint2*)(vthi + o) = hv;
        *(uint2*)(vtlo + o) = lv;
    }
}

// ---------------------------------------------------------------------------
// Split-bf16 MFMA GEMM: C[1024 x NG] = A[1024 x KG] * B[NG x KG]^T  per batch
// (both operands K-contiguous, hi/lo components). 128x128 tile, BK=32,
// 256 threads = 4 waves, each wave 64x64 via 4x4 grid of 16x16x32 MFMA,
// 3 passes: hi*hi + hi*lo + lo*hi.
// ---------------------------------------------------------------------------
template <int KG, int NG>
__global__ __launch_bounds__(256) void gemm_hilo(const ushort_t* __restrict__ Ahi,
                                                 const ushort_t* __restrict__ Alo,
                                                 const ushort_t* __restrict__ Bhi,
                                                 const ushort_t* __restrict__ Blo,
                                                 float* __restrict__ C) {
    __shared__ ushort_t sm[4][128 * 32];   // comps: Ahi, Alo, Bhi, Blo (8 KB each)

    const int b   = blockIdx.z;
    const int bm0 = blockIdx.x * 128;
    const int bn0 = blockIdx.y * 128;
    const int tid = threadIdx.x;
    const int w   = tid >> 6;
    const int lane = tid & 63;

    const size_t Ab = (size_t)b * 1024 * KG + (size_t)bm0 * KG;
    const size_t Bb = (size_t)b * NG * KG + (size_t)bn0 * KG;
    // wave w stages component w (Ahi/Alo/Bhi/Blo)
    const ushort_t* src = (w == 0) ? Ahi + Ab : (w == 1) ? Alo + Ab
                        : (w == 2) ? Bhi + Bb : Blo + Bb;
    src += (size_t)(lane >> 2) * KG + (lane & 3) * 8;
    ushort_t* lbase = &sm[w][0];

    const int wm = (w & 1) * 64, wn = (w >> 1) * 64;
    const int mf = lane & 15, q = lane >> 4;
    const int aoff = (wm + mf) * 32 + q * 8;
    const int boff = (wn + mf) * 32 + q * 8;

    f32x4 acc[4][4] = {};

    for (int k0 = 0; k0 < KG; k0 += 32) {
        __syncthreads();   // previous iteration's frag reads done before overwrite
#pragma unroll
        for (int t = 0; t < 8; ++t)
            __builtin_amdgcn_global_load_lds((const AS1 u32*)(src + k0 + (size_t)t * 16 * KG),
                                             (AS3 u32*)(lbase + t * 512), 16, 0, 0);
        __syncthreads();   // staging complete (barrier drains vmcnt)

        short8 ah[4], al[4], bh[4], bl[4];
#pragma unroll
        for (int i = 0; i < 4; ++i) {
            ah[i] = *(const short8*)&sm[0][aoff + i * 512];
            al[i] = *(const short8*)&sm[1][aoff + i * 512];
            bh[i] = *(const short8*)&sm[2][boff + i * 512];
            bl[i] = *(const short8*)&sm[3][boff + i * 512];
        }
#pragma unroll
        for (int i = 0; i < 4; ++i)
#pragma unroll
            for (int j = 0; j < 4; ++j) {
                acc[i][j] = __builtin_amdgcn_mfma_f32_16x16x32_bf16(ah[i], bh[j], acc[i][j], 0, 0, 0);
                acc[i][j] = __builtin_amdgcn_mfma_f32_16x16x32_bf16(ah[i], bl[j], acc[i][j], 0, 0, 0);
                acc[i][j] = __builtin_amdgcn_mfma_f32_16x16x32_bf16(al[i], bh[j], acc[i][j], 0, 0, 0);
            }
    }

    // epilogue: C/D layout col = lane&15, row = q*4 + reg  [m89-verified]
    float* Cb = C + (size_t)b * 1024 * NG + (size_t)bm0 * NG + bn0;
#pragma unroll
    for (int i = 0; i < 4; ++i)
#pragma unroll
        for (int j = 0; j < 4; ++j)
#pragma unroll
            for (int r = 0; r < 4; ++r)
                Cb[(size_t)(wm + i * 16 + q * 4 + r) * NG + wn + j * 16 + mf] = acc[i][j][r];
}

// ---------------------------------------------------------------------------
// Row softmax in place + pack P into bf16 hi/lo for the PV gemm
// ---------------------------------------------------------------------------
__global__ __launch_bounds__(256) void softmax_conv(float* __restrict__ S,
                                                    ushort_t* __restrict__ Phi,
                                                    ushort_t* __restrict__ Plo) {
    const size_t row = blockIdx.x;
    float* p = S + row * LK;
    const int t = threadIdx.x;

    float4 v = *(float4*)(p + (t << 2));
    float m = fmaxf(fmaxf(v.x, v.y), fmaxf(v.z, v.w));
#pragma unroll
    for (int off = 1; off < 64; off <<= 1)
        m = fmaxf(m, __shfl_xor(m, off, 64));

    __shared__ float redm[4];
    __shared__ float reds[4];
    const int wave = t >> 6, lane = t & 63;
    if (lane == 0) redm[wave] = m;
    __syncthreads();
    m = fmaxf(fmaxf(redm[0], redm[1]), fmaxf(redm[2], redm[3]));

    v.x = __expf(v.x - m); v.y = __expf(v.y - m);
    v.z = __expf(v.z - m); v.w = __expf(v.w - m);
    float s = (v.x + v.y) + (v.z + v.w);
#pragma unroll
    for (int off = 1; off < 64; off <<= 1)
        s += __shfl_xor(s, off, 64);
    if (lane == 0) reds[wave] = s;
    __syncthreads();
    s = (reds[0] + reds[1]) + (reds[2] + reds[3]);

    const float inv = 1.0f / s;
    v.x *= inv; v.y *= inv; v.z *= inv; v.w *= inv;
    *(float4*)(p + (t << 2)) = v;

    u32 h0, h1, l0, l1;
    split2(v.x, v.y, h0, l0); split2(v.z, v.w, h1, l1);
    uint2 hv; hv.x = h0; hv.y = h1;
    uint2 lv; lv.x = l0; lv.y = l1;
    *(uint2*)(Phi + row * LK + (t << 2)) = hv;
    *(uint2*)(Plo + row * LK + (t << 2)) = lv;
}

// ===========================================================================
// Fallback fp32 path (round-1 kernels) — used only if ws_size is too small
// ===========================================================================
constexpr int BM = 64, BN = 64, BK = 16, PAD = 4;

__global__ __launch_bounds__(256) void gemm_qvt(const float* __restrict__ Q,
                                                const float* __restrict__ V,
                                                float* __restrict__ S) {
    __shared__ __align__(16) float sA[BK][BM + PAD];
    __shared__ __align__(16) float sB[BK][BN + PAD];
    const int b = blockIdx.z;
    const float* Qb = Q + (size_t)b * LQ * DD + (size_t)blockIdx.x * BM * DD;
    const float* Vb = V + (size_t)b * LK * DD + (size_t)blockIdx.y * BN * DD;
    float*       Sb = S + (size_t)b * LQ * LK;
    const int tid = threadIdx.x;
    const int tx = tid & 15, ty = tid >> 4;
    const int lr = tid >> 2, lc = (tid & 3) << 2;
    float acc[4][4] = {};
    for (int k0 = 0; k0 < DD; k0 += BK) {
        float4 qa = *(const float4*)(Qb + (size_t)lr * DD + k0 + lc);
        float4 va = *(const float4*)(Vb + (size_t)lr * DD + k0 + lc);
        __syncthreads();
        sA[lc + 0][lr] = qa.x; sA[lc + 1][lr] = qa.y; sA[lc + 2][lr] = qa.z; sA[lc + 3][lr] = qa.w;
        sB[lc + 0][lr] = va.x; sB[lc + 1][lr] = va.y; sB[lc + 2][lr] = va.z; sB[lc + 3][lr] = va.w;
        __syncthreads();
#pragma unroll
        for (int k = 0; k < BK; ++k) {
            float4 a4 = *(const float4*)&sA[k][ty << 2];
            float4 b4 = *(const float4*)&sB[k][tx << 2];
            float a[4] = {a4.x, a4.y, a4.z, a4.w};
            float bb[4] = {b4.x, b4.y, b4.z, b4.w};
#pragma unroll
            for (int i = 0; i < 4; ++i)
#pragma unroll
                for (int j = 0; j < 4; ++j) acc[i][j] = fmaf(a[i], bb[j], acc[i][j]);
        }
    }
    const int r0 = blockIdx.x * BM + (ty << 2), c0 = blockIdx.y * BN + (tx << 2);
#pragma unroll
    for (int i = 0; i < 4; ++i) {
        float4 o = {acc[i][0], acc[i][1], acc[i][2], acc[i][3]};
        *(float4*)(Sb + (size_t)(r0 + i) * LK + c0) = o;
    }
}

__global__ __launch_bounds__(256) void softmax_rows(float* __restrict__ S) {
    float* p = S + (size_t)blockIdx.x * LK;
    const int t = threadIdx.x;
    float4 v = *(float4*)(p + (t << 2));
    float m = fmaxf(fmaxf(v.x, v.y), fmaxf(v.z, v.w));
#pragma unroll
    for (int off = 1; off < 64; off <<= 1) m = fmaxf(m, __shfl_xor(m, off, 64));
    __shared__ float redm[4]; __shared__ float reds[4];
    const int wave = t >> 6, lane = t & 63;
    if (lane == 0) redm[wave] = m;
    __syncthreads();
    m = fmaxf(fmaxf(redm[0], redm[1]), fmaxf(redm[2], redm[3]));
    v.x = __expf(v.x - m); v.y = __expf(v.y - m); v.z = __expf(v.z - m); v.w = __expf(v.w - m);
    float s = (v.x + v.y) + (v.z + v.w);
#pragma unroll
    for (int off = 1; off < 64; off <<= 1) s += __shfl_xor(s, off, 64);
    if (lane == 0) reds[wave] = s;
    __syncthreads();
    s = (reds[0] + reds[1]) + (reds[2] + reds[3]);
    const float inv = 1.0f / s;
    v.x *= inv; v.y *= inv; v.z *= inv; v.w *= inv;
    *(float4*)(p + (t << 2)) = v;
}

__global__ __launch_bounds__(256) void gemm_pv(const float* __restrict__ P,
                                               const float* __restrict__ V,
                                               float* __restrict__ C) {
    __shared__ __align__(16) float sA[BK][BM + PAD];
    __shared__ __align__(16) float sB[BK][BN + PAD];
    const int b = blockIdx.z;
    const float* Pb = P + (size_t)b * LQ * LK + (size_t)blockIdx.x * BM * LK;
    const float* Vb = V + (size_t)b * LK * DD;
    float*       Cb = C + (size_t)b * LQ * DD;
    const int tid = threadIdx.x;
    const int tx = tid & 15, ty = tid >> 4;
    const int lr = tid >> 2, lc = (tid & 3) << 2;
    const int bkr = tid >> 4, bcg = (tid & 15) << 2;
    const int n0 = blockIdx.y * BN;
    float acc[4][4] = {};
    for (int k0 = 0; k0 < LK; k0 += BK) {
        float4 pa = *(const float4*)(Pb + (size_t)lr * LK + k0 + lc);
        float4 vb = *(const float4*)(Vb + (size_t)(k0 + bkr) * DD + n0 + bcg);
        __syncthreads();
        sA[lc + 0][lr] = pa.x; sA[lc + 1][lr] = pa.y; sA[lc + 2][lr] = pa.z; sA[lc + 3][lr] = pa.w;
        *(float4*)&sB[bkr][bcg] = vb;
        __syncthreads();
#pragma unroll
        for (int k = 0; k < BK; ++k) {
            float4 a4 = *(const float4*)&sA[k][ty << 2];
            float4 b4 = *(const float4*)&sB[k][tx << 2];
            float a[4] = {a4.x, a4.y, a4.z, a4.w};
            float bb[4] = {b4.x, b4.y, b4.z, b4.w};
#pragma unroll
            for (int i = 0; i < 4; ++i)
#pragma unroll
                for (int j = 0; j < 4; ++j) acc[i][j] = fmaf(a[i], bb[j], acc[i][j]);
        }
    }
    const int r0 = blockIdx.x * BM + (ty << 2), c0 = n0 + (tx << 2);
#pragma unroll
    for (int i = 0; i < 4; ++i) {
        float4 o = {acc[i][0], acc[i][1], acc[i][2], acc[i][3]};
        *(float4*)(Cb + (size_t)(r0 + i) * DD + c0) = o;
    }
}

// ---------------------------------------------------------------------------
extern "C" void kernel_launch(void* const* d_in, const int* in_sizes, int n_in,
                              void* d_out, int out_size, void* d_ws, size_t ws_size,
                              hipStream_t stream) {
    const float* Q = (const float*)d_in[0];
    const float* V = (const float*)d_in[1];

    float* ctx  = (float*)d_out;                       // [16,1024,512]
    float* attn = ctx + (size_t)BATCH * LQ * DD;       // [16,1024,1024]

    const size_t NQ = (size_t)BATCH * LQ * DD;   // 8,388,608
    const size_t NP = (size_t)BATCH * LQ * LK;   // 16,777,216
    const size_t needed = (6 * NQ + 2 * NP) * sizeof(ushort_t);  // 160 MiB

    if (ws_size >= needed) {
        ushort_t* w = (ushort_t*)d_ws;
        ushort_t* Qhi = w;            ushort_t* Qlo = w + NQ;
        ushort_t* Vhi = w + 2 * NQ;   ushort_t* Vlo = w + 3 * NQ;
        ushort_t* Vthi = w + 4 * NQ;  ushort_t* Vtlo = w + 5 * NQ;
        ushort_t* Phi = w + 6 * NQ;   ushort_t* Plo = w + 6 * NQ + NP;

        convert_q<<<dim3(NQ / (256 * 8)), 256, 0, stream>>>(Q, Qhi, Qlo);
        convert_v<<<dim3(DD / 32, LK / 32, BATCH), 256, 0, stream>>>(V, Vhi, Vlo, Vthi, Vtlo);
        // S = Q @ V^T  (A: [1024,512] k-contig, B: [1024,512] k-contig)
        gemm_hilo<DD, LK><<<dim3(8, 8, BATCH), 256, 0, stream>>>(Qhi, Qlo, Vhi, Vlo, attn);
        // softmax in place + pack P
        softmax_conv<<<dim3(BATCH * LQ), 256, 0, stream>>>(attn, Phi, Plo);
        // context = P @ V  (A: P [1024,1024] k-contig, B: Vt [512,1024] k-contig)
        gemm_hilo<LK, DD><<<dim3(8, 4, BATCH), 256, 0, stream>>>(Phi, Plo, Vthi, Vtlo, ctx);
    } else {
        // fallback: fp32 path (correct, slower)
        gemm_qvt<<<dim3(LQ / BM, LK / BN, BATCH), 256, 0, stream>>>(Q, V, attn);
        softmax_rows<<<dim3(BATCH * LQ), 256, 0, stream>>>(attn);
        gemm_pv<<<dim3(LQ / BM, DD / BN, BATCH), 256, 0, stream>>>(attn, V, ctx);
    }
}